// Round 13
// baseline (252.858 us; speedup 1.0000x reference)
//
#include <hip/hip_runtime.h>
#include <hip/hip_bf16.h>

// B=4, T=1024, E=512, H=8. Two-pass attention, all matmuls on one GEMM:
//   cast5 -> QK proj (fused dispatch) + Vt (=Wv.x^T) -> S=QK^T*a
//   -> softmax(S-mask) in place -> O=P.V -> out GEMM split-K=8 + reduce(+bias).
// gemm_bt2: C = alpha*A.B^T, 256x256 tile, BK=32, 512 thr / 8 waves (2M x 4N),
// 4-buffer LDS (4 x 32KB = 128KB), phase-split schedule (T3+T4+T5):
// per K-tile 2 phases x 16 MFMA; stage(t+2) spread across phases; vmcnt(4)
// once per tile (t+1 forced, t+2 in flight). 4-buffer rotation => stage target
// is always >= 2 tiles from any live read: no overwrite race by construction.
// T1 bijective XCD swizzle (all grids % 8 == 0).
// REGISTER LAW (R5/R8/R9/R10): (512,1) -> ~116 arch VGPR + 128 acc, no spill;
// (512,2)->cap128 / (512,4)->cap64 spill the accumulator (scratch-write sig).
// Fragment-major LDS = conflict-free ds_read_b128 (SQ_LDS_BANK_CONFLICT=0).
// Layouts: Q,K [b,t,h,e] ld 4096; Vt [h*e, b*t]; S/P [b,h,q,k]; O [b,t,h*e].

typedef short bf16x8 __attribute__((ext_vector_type(8)));
typedef float f32x4 __attribute__((ext_vector_type(4)));
typedef unsigned short u16x8 __attribute__((ext_vector_type(8)));

__device__ __forceinline__ unsigned short f2bf(float f) {
  unsigned int u = __float_as_uint(f);
  u += 0x7FFFu + ((u >> 16) & 1u);            // RNE, finite inputs
  return (unsigned short)(u >> 16);
}
__device__ __forceinline__ float bf2f(unsigned short s) {
  return __uint_as_float(((unsigned int)s) << 16);
}

typedef const __attribute__((address_space(1))) unsigned int* gas1_t;
typedef __attribute__((address_space(3))) unsigned int* las3_t;

__device__ __forceinline__ void gload16(const unsigned short* g, unsigned short* l) {
  __builtin_amdgcn_global_load_lds((gas1_t)g, (las3_t)l, 16, 0, 0);
}

__device__ __forceinline__ void store_val(unsigned short* p, float v) { *p = f2bf(v); }
__device__ __forceinline__ void store_val(float* p, float v) { *p = v; }

// ---------------- 256x256-tile BT GEMM, BK=32, 4-buf phase-split ----------------
// Fragment-major LDS: buffer p at elems [p*16384,+16384): A frags [0,8192)
// (frag m=0..15 holds rows m*16+l15, slot=lane), B frags [8192,16384).
template<typename OutT>
__global__ __launch_bounds__(512, 1) void gemm_bt2(
    const unsigned short* __restrict__ A, const unsigned short* __restrict__ B,
    OutT* __restrict__ C,
    int K, int lda, int ldb, int ldc, int zshift,
    long long sAb, long long sAh, long long sBb, long long sBh,
    long long sCb, long long sCh, float alpha)
{
  const int tid  = threadIdx.x;
  const int lane = tid & 63;
  const int wave = tid >> 6;
  const int l15 = lane & 15, lhi = lane >> 4;
  const int wm = wave >> 2, wn = wave & 3;           // 2M x 4N wave grid

  // T1: bijective XCD chunk swizzle (nwg % 8 == 0 for every launch here)
  const int nx = gridDim.x, nxy = gridDim.x * gridDim.y;
  const int nwg = nxy * gridDim.z;
  int flat = blockIdx.x + nx * blockIdx.y + nxy * blockIdx.z;
  flat = (flat & 7) * (nwg >> 3) + (flat >> 3);
  const int bz = flat / nxy;
  const int rem = flat - bz * nxy;
  const int by = rem / nx;
  const int bx = rem - by * nx;

  const int bb = bz >> zshift, hh = bz & ((1 << zshift) - 1);
  const long long m0 = (long long)by * 256;
  const long long n0 = (long long)bx * 256;

  const unsigned short* Ab = A + bb * sAb + hh * sAh;
  const unsigned short* Bb = B + bb * sBb + hh * sBh;

  __shared__ __align__(16) unsigned short lds[65536];  // 128 KB, 4 buffers

  // per-wave staging sources: frag f = c*8+wave, c=0,1 (covers all 16 frags)
  const unsigned short* gA[2];
  const unsigned short* gB[2];
  int fidx[2];
#pragma unroll
  for (int c = 0; c < 2; ++c) {
    const int f = c * 8 + wave;
    fidx[c] = f;
    gA[c] = Ab + (size_t)(m0 + f * 16 + l15) * lda + lhi * 8;
    gB[c] = Bb + (size_t)(n0 + f * 16 + l15) * ldb + lhi * 8;
  }

  // stage A-half or B-half of K-tile n into buffer p (2 gload16 per wave)
  auto stageA = [&](int n, int p) {
    unsigned short* dst = lds + p * 16384;
    const int ko = n * 32;
#pragma unroll
    for (int c = 0; c < 2; ++c) gload16(gA[c] + ko, dst + fidx[c] * 512);
  };
  auto stageB = [&](int n, int p) {
    unsigned short* dst = lds + p * 16384 + 8192;
    const int ko = n * 32;
#pragma unroll
    for (int c = 0; c < 2; ++c) gload16(gB[c] + ko, dst + fidx[c] * 512);
  };

  f32x4 acc[8][4];
#pragma unroll
  for (int m = 0; m < 8; ++m)
#pragma unroll
    for (int n = 0; n < 4; ++n) acc[m][n] = (f32x4){0.f, 0.f, 0.f, 0.f};

  const int nt = K >> 5;                // K-tiles of 32
  // prologue: 2-deep prefetch (tiles 0,1 -> bufs 0,1)
  stageA(0, 0); stageB(0, 0);
  stageA(1, 1); stageB(1, 1);
  asm volatile("s_waitcnt vmcnt(4)" ::: "memory");   // tile 0 landed
  __builtin_amdgcn_sched_barrier(0);
  __builtin_amdgcn_s_barrier();
  __builtin_amdgcn_sched_barrier(0);

  for (int t = 0; t < nt; ++t) {
    const int p = t & 3;
    const unsigned short* base = lds + p * 16384;
    const bool pref = (t + 2 < nt);
    const int pd = (t + 2) & 3;        // stage target: never read during t, t+1

    // ---- phase 0: A-quad0 + all B reads; stage A(t+2); 16 MFMA ----
    bf16x8 af[4], bf[4];
#pragma unroll
    for (int i = 0; i < 4; ++i)
      af[i] = *(const bf16x8*)(base + (wm * 8 + i) * 512 + lane * 8);
#pragma unroll
    for (int i = 0; i < 4; ++i)
      bf[i] = *(const bf16x8*)(base + 8192 + (wn * 4 + i) * 512 + lane * 8);
    if (pref) stageA(t + 2, pd);
    __builtin_amdgcn_s_barrier();
    asm volatile("s_waitcnt lgkmcnt(0)" ::: "memory");
    __builtin_amdgcn_sched_barrier(0);
    __builtin_amdgcn_s_setprio(1);
#pragma unroll
    for (int mf = 0; mf < 4; ++mf)
#pragma unroll
      for (int nf = 0; nf < 4; ++nf)
        acc[mf][nf] = __builtin_amdgcn_mfma_f32_16x16x32_bf16(af[mf], bf[nf], acc[mf][nf], 0, 0, 0);
    __builtin_amdgcn_s_setprio(0);
    __builtin_amdgcn_s_barrier();
    __builtin_amdgcn_sched_barrier(0);

    // ---- phase 1: A-quad1 reads; stage B(t+2); 16 MFMA; counted vmcnt ----
#pragma unroll
    for (int i = 0; i < 4; ++i)
      af[i] = *(const bf16x8*)(base + (wm * 8 + 4 + i) * 512 + lane * 8);
    if (pref) stageB(t + 2, pd);
    __builtin_amdgcn_s_barrier();
    asm volatile("s_waitcnt lgkmcnt(0)" ::: "memory");
    __builtin_amdgcn_sched_barrier(0);
    __builtin_amdgcn_s_setprio(1);
#pragma unroll
    for (int mf = 0; mf < 4; ++mf)
#pragma unroll
      for (int nf = 0; nf < 4; ++nf)
        acc[mf + 4][nf] = __builtin_amdgcn_mfma_f32_16x16x32_bf16(af[mf], bf[nf], acc[mf + 4][nf], 0, 0, 0);
    __builtin_amdgcn_s_setprio(0);
    // T4: counted drain -- tile t+1 forced complete; t+2's 4 loads in flight
    if (pref) asm volatile("s_waitcnt vmcnt(4)" ::: "memory");
    else      asm volatile("s_waitcnt vmcnt(0)" ::: "memory");
    __builtin_amdgcn_sched_barrier(0);
    __builtin_amdgcn_s_barrier();
    __builtin_amdgcn_sched_barrier(0);
  }

  // C/D layout (m89/m91): col = lane&15, row = (lane>>4)*4 + reg
  OutT* Cb = C + bb * sCb + hh * sCh;
#pragma unroll
  for (int mf = 0; mf < 8; ++mf) {
#pragma unroll
    for (int nf = 0; nf < 4; ++nf) {
      const long long col = n0 + wn * 64 + nf * 16 + l15;
#pragma unroll
      for (int r = 0; r < 4; ++r) {
        const long long row = m0 + wm * 128 + mf * 16 + lhi * 4 + r;
        store_val(Cb + (size_t)row * ldc + col, acc[mf][nf][r] * alpha);
      }
    }
  }
}

// ---------------- split-K reduce: out = sum(partials) + bias ----------------
__global__ __launch_bounds__(256) void reduce_kernel(
    const float* __restrict__ P, const float* __restrict__ bias,
    float* __restrict__ out)
{
  const int i = blockIdx.x * 256 + threadIdx.x;      // 0..524287 float4s
  const int col4 = i & 127;
  const float4* p4 = (const float4*)P + i;
  float4 s = p4[0];
#pragma unroll
  for (int z = 1; z < 8; ++z) {
    float4 v = p4[(size_t)z * 524288];
    s.x += v.x; s.y += v.y; s.z += v.z; s.w += v.w;
  }
  float4 b = ((const float4*)bias)[col4];
  s.x += b.x; s.y += b.y; s.z += b.z; s.w += b.w;
  ((float4*)out)[i] = s;
}

// ---------------- fused fp32 -> bf16 cast of all 5 tensors ----------------
__global__ __launch_bounds__(256) void cast5_kernel(
    const float* __restrict__ s0, const float* __restrict__ s1,
    const float* __restrict__ s2, const float* __restrict__ s3,
    const float* __restrict__ s4, unsigned short* __restrict__ dst)
{
  const int seg = blockIdx.x >> 11;
  const int off = (blockIdx.x & 2047) * 256 + threadIdx.x;
  const float* s = s0;
  if (seg == 1) s = s1; else if (seg == 2) s = s2;
  else if (seg == 3) s = s3; else if (seg == 4) s = s4;
  float4 v = ((const float4*)s)[off];
  ushort4 o;
  o.x = f2bf(v.x); o.y = f2bf(v.y); o.z = f2bf(v.z); o.w = f2bf(v.w);
  ((ushort4*)dst)[(size_t)seg * 524288 + off] = o;
}

// ---------------- in-place row softmax over S (bf16), logit = S - mask ----------------
__global__ __launch_bounds__(256) void softmax_kernel(
    unsigned short* __restrict__ S, const float* __restrict__ mask)
{
  const int wave = threadIdx.x >> 6;
  const int lane = threadIdx.x & 63;
  const long long row = (long long)blockIdx.x * 4 + wave;   // 0..32767
  const int q = (int)(row & 1023);
  const int b = (int)(row >> 13);
  unsigned short* Srow = S + row * 1024;
  const float* mrow = mask + ((size_t)b * 1024 + q) * 1024;

  u16x8 sv0 = ((const u16x8*)Srow)[lane * 2];
  u16x8 sv1 = ((const u16x8*)Srow)[lane * 2 + 1];
  float mk[16];
  const float4* m4 = (const float4*)mrow + lane * 4;
#pragma unroll
  for (int t = 0; t < 4; ++t) {
    float4 v = m4[t];
    mk[t * 4 + 0] = v.x; mk[t * 4 + 1] = v.y; mk[t * 4 + 2] = v.z; mk[t * 4 + 3] = v.w;
  }

  float lg[16];
#pragma unroll
  for (int j = 0; j < 8; ++j) lg[j] = bf2f(sv0[j]) - mk[j];
#pragma unroll
  for (int j = 0; j < 8; ++j) lg[8 + j] = bf2f(sv1[j]) - mk[8 + j];

  float mx = lg[0];
#pragma unroll
  for (int j = 1; j < 16; ++j) mx = fmaxf(mx, lg[j]);
#pragma unroll
  for (int off = 32; off > 0; off >>= 1) mx = fmaxf(mx, __shfl_xor(mx, off));

  float ex[16], sm = 0.f;
#pragma unroll
  for (int j = 0; j < 16; ++j) { ex[j] = __expf(lg[j] - mx); sm += ex[j]; }
#pragma unroll
  for (int off = 32; off > 0; off >>= 1) sm += __shfl_xor(sm, off);
  const float rinv = 1.0f / sm;

  u16x8 o0, o1;
#pragma unroll
  for (int j = 0; j < 8; ++j) o0[j] = f2bf(ex[j] * rinv);
#pragma unroll
  for (int j = 0; j < 8; ++j) o1[j] = f2bf(ex[8 + j] * rinv);
  ((u16x8*)Srow)[lane * 2] = o0;
  ((u16x8*)Srow)[lane * 2 + 1] = o1;
}

extern "C" void kernel_launch(void* const* d_in, const int* in_sizes, int n_in,
                              void* d_out, int out_size, void* d_ws, size_t ws_size,
                              hipStream_t stream) {
  const float* x    = (const float*)d_in[0];
  const float* mask = (const float*)d_in[1];
  const float* Wk   = (const float*)d_in[2];
  const float* Wq   = (const float*)d_in[3];
  const float* Wv   = (const float*)d_in[4];
  const float* Wu   = (const float*)d_in[5];
  const float* bu   = (const float*)d_in[6];

  const size_t MB = 1024 * 1024;
  if (ws_size < 212 * MB) return;
  char* ws = (char*)d_ws;
  unsigned short* xb  = (unsigned short*)(ws + 0 * MB);    // 4MB  [4096,512]
  unsigned short* Wqb = (unsigned short*)(ws + 4 * MB);
  unsigned short* Wkb = (unsigned short*)(ws + 8 * MB);
  unsigned short* Wvb = (unsigned short*)(ws + 12 * MB);
  unsigned short* Wub = (unsigned short*)(ws + 16 * MB);
  unsigned short* Qb  = (unsigned short*)(ws + 20 * MB);   // 32MB [b,t,h,e]
  unsigned short* Kb  = (unsigned short*)(ws + 52 * MB);   // 32MB
  unsigned short* Vt  = (unsigned short*)(ws + 84 * MB);   // 32MB [h*e, b*t]
  unsigned short* Sb  = (unsigned short*)(ws + 116 * MB);  // 64MB [b,h,q,k]
  unsigned short* Ob  = (unsigned short*)(ws + 180 * MB);  // 32MB [b,t,h*e]
  float* Pk = (float*)(ws + 20 * MB);  // split-K partials overlay Qb/Kb (dead post-attn)

  cast5_kernel<<<5 * 2048, 256, 0, stream>>>(x, Wq, Wk, Wv, Wu, xb);

  // Q and K projections fused: z=0 -> Wqb/Qb, z=1 -> Wkb/Kb (strides 2M / 16M elems)
  gemm_bt2<unsigned short><<<dim3(16, 16, 2), 512, 0, stream>>>(
      xb, Wqb, Qb, 512, 512, 512, 4096, 0,
      0, 0, 2097152LL, 0, 16777216LL, 0, 1.0f);
  // Vt = Wv.x^T
  gemm_bt2<unsigned short><<<dim3(16, 16, 1), 512, 0, stream>>>(
      Wvb, xb, Vt, 512, 512, 512, 4096, 0, 0, 0, 0, 0, 0, 0, 1.0f);

  // S = (1/sqrt(512)) * Q.K^T per (b,h)   (M=N=1024, K=512, 32 batches)
  gemm_bt2<unsigned short><<<dim3(4, 4, 32), 512, 0, stream>>>(
      Qb, Kb, Sb, 512, 4096, 4096, 1024, 3,
      4194304LL, 512LL, 4194304LL, 512LL, 8388608LL, 1048576LL,
      0.044194173824159216f);

  // P = softmax(S - mask) in place
  softmax_kernel<<<8192, 256, 0, stream>>>(Sb, mask);

  // O = P.V   (M=1024, N=512, K=1024, 32 batches)
  gemm_bt2<unsigned short><<<dim3(2, 4, 32), 512, 0, stream>>>(
      Sb, Vt, Ob, 1024, 1024, 4096, 4096, 3,
      8388608LL, 1048576LL, 1024LL, 2097152LL, 4194304LL, 512LL, 1.0f);

  // out partials: split-K=8 over K=4096 (M=4096, N=512, slice=512)
  gemm_bt2<float><<<dim3(2, 16, 8), 512, 0, stream>>>(
      Ob, Wub, Pk, 512, 4096, 4096, 512, 0,
      512LL, 0, 512LL, 0, 2097152LL, 0, 1.0f);

  // out = sum_z Pk[z] + bu
  reduce_kernel<<<2048, 256, 0, stream>>>(Pk, bu, (float*)d_out);
}

// Round 14
// 248.782 us; speedup vs baseline: 1.0164x; 1.0164x over previous
//
#include <hip/hip_runtime.h>
#include <hip/hip_bf16.h>

// B=4, T=1024, E=512, H=8. Two-pass attention, all matmuls on one GEMM:
//   cast5 -> QK proj (fused dispatch) + Vt (=Wv.x^T) -> S=QK^T*a
//   -> softmax(S-mask) in place -> O=P.V -> out GEMM split-K=8 + reduce(+bias).
// gemm_bt2: C = alpha*A.B^T, 256x256 tile, BK=64, 512 thr / 8 waves (2M x 4N),
// 2 dbuf x 64KB LDS. Staggered-wavefront 4-phase schedule (T3+T4+T5):
//   phase p = C-quadrant (mf 2p,2p+1 x all nf x K=64) = 16 MFMA.
//   Staging of tile t+1 during t, issue order G1..G8 =
//     p0: B-half0 (G1,G2) | p1: B-half1 (G3,G4) | p2: Ac0,Ac1 (G5,G6)
//     p3: Ac2,Ac3 (G7,G8), where A-chunk j = quadrant j's frags (both halves).
//   Completion ledger (per-wave vmcnt + barrier = cross-wave wavefront):
//     t+1.p0 needs G1..G6 -> vmcnt(2) at t.p3-end
//     t+1.p2 needs G7,G8  -> vmcnt(4) at t+1.p1-end (6 outstanding - pair)
//   Never drain to 0 mid-loop. Pair-granular forcing (robust to intra-phase
//   load reorder). Raw s_barrier (no lgkm drain needed: no ds_writes; ds_read
//   visibility is per-wave data-dep).
// REGISTER LAW (R5/R8/R9/R10): (512,1) -> no spill; (512,2)/(512,4) spill acc.
// Fragment-major LDS = conflict-free ds_read_b128 (SQ_LDS_BANK_CONFLICT=0).
// T1 bijective XCD swizzle (all grids % 8 == 0).
// Layouts: Q,K [b,t,h,e] ld 4096; Vt [h*e, b*t]; S/P [b,h,q,k]; O [b,t,h*e].

typedef short bf16x8 __attribute__((ext_vector_type(8)));
typedef float f32x4 __attribute__((ext_vector_type(4)));
typedef unsigned short u16x8 __attribute__((ext_vector_type(8)));

__device__ __forceinline__ unsigned short f2bf(float f) {
  unsigned int u = __float_as_uint(f);
  u += 0x7FFFu + ((u >> 16) & 1u);            // RNE, finite inputs
  return (unsigned short)(u >> 16);
}
__device__ __forceinline__ float bf2f(unsigned short s) {
  return __uint_as_float(((unsigned int)s) << 16);
}

typedef const __attribute__((address_space(1))) unsigned int* gas1_t;
typedef __attribute__((address_space(3))) unsigned int* las3_t;

__device__ __forceinline__ void gload16(const unsigned short* g, unsigned short* l) {
  __builtin_amdgcn_global_load_lds((gas1_t)g, (las3_t)l, 16, 0, 0);
}

__device__ __forceinline__ void store_val(unsigned short* p, float v) { *p = f2bf(v); }
__device__ __forceinline__ void store_val(float* p, float v) { *p = v; }

// ---------------- 256x256-tile BT GEMM, BK=64, staggered 4-phase ----------------
// Frag (m,ks): A at (m*2+ks)*512, B at 16384+(n*2+ks)*512 elems within the
// 32768-elem buffer (bsel*32768). Frag slot = lane (16B): row m*16+l15,
// k-chunk ks*32+lhi*8. One gload16 = one frag (64 lanes x 16B).
template<typename OutT>
__global__ __launch_bounds__(512, 1) void gemm_bt2(
    const unsigned short* __restrict__ A, const unsigned short* __restrict__ B,
    OutT* __restrict__ C,
    int K, int lda, int ldb, int ldc, int zshift,
    long long sAb, long long sAh, long long sBb, long long sBh,
    long long sCb, long long sCh, float alpha)
{
  const int tid  = threadIdx.x;
  const int lane = tid & 63;
  const int wave = tid >> 6;
  const int l15 = lane & 15, lhi = lane >> 4;
  const int wm = wave >> 2, wn = wave & 3;           // 2M x 4N wave grid

  // T1: bijective XCD chunk swizzle (nwg % 8 == 0 for every launch here)
  const int nx = gridDim.x, nxy = gridDim.x * gridDim.y;
  const int nwg = nxy * gridDim.z;
  int flat = blockIdx.x + nx * blockIdx.y + nxy * blockIdx.z;
  flat = (flat & 7) * (nwg >> 3) + (flat >> 3);
  const int bz = flat / nxy;
  const int rem = flat - bz * nxy;
  const int by = rem / nx;
  const int bx = rem - by * nx;

  const int bb = bz >> zshift, hh = bz & ((1 << zshift) - 1);
  const long long m0 = (long long)by * 256;
  const long long n0 = (long long)bx * 256;

  const unsigned short* Ab = A + bb * sAb + hh * sAh;
  const unsigned short* Bb = B + bb * sBb + hh * sBh;

  __shared__ __align__(16) unsigned short lds[65536];  // 128 KB, 2 buffers

  // per-wave staging bases (see ledger in header comment)
  const int w = wave;
  const unsigned short* pB = Bb + (size_t)(n0 + (w >> 1) * 16 + l15) * ldb
                                + (w & 1) * 32 + lhi * 8;
  const unsigned short* pA = Ab + (size_t)(m0 + ((w >> 1) & 1) * 16 + (w >> 2) * 128 + l15) * lda
                                + (w & 1) * 32 + lhi * 8;
  const int abase = ((w >> 1) & 1) * 2 + (w >> 2) * 16 + (w & 1);

  // stage B-half h (cols h*128..h*128+128): frags bfi = 16h+w, 16h+8+w
  auto stageBH = [&](int h, int k0, int bsel) {
    unsigned short* dst = lds + bsel * 32768 + 16384;
    gload16(pB + (size_t)(h * 128) * ldb + k0,      dst + (16 * h + w) * 512);
    gload16(pB + (size_t)(h * 128 + 64) * ldb + k0, dst + (16 * h + 8 + w) * 512);
  };
  // stage A-chunk j (quadrant j frags, both wm halves): afi = 4j + abase
  auto stageAC = [&](int j, int k0, int bsel) {
    gload16(pA + (size_t)(j * 32) * lda + k0, lds + bsel * 32768 + (4 * j + abase) * 512);
  };

  f32x4 acc[8][4];
#pragma unroll
  for (int m = 0; m < 8; ++m)
#pragma unroll
    for (int n = 0; n < 4; ++n) acc[m][n] = (f32x4){0.f, 0.f, 0.f, 0.f};

  const int nt = K >> 6;                // K-tiles of 64
  // prologue: stage tile 0 in canonical G1..G8 order, full drain once
  stageBH(0, 0, 0); stageBH(1, 0, 0);
  stageAC(0, 0, 0); stageAC(1, 0, 0); stageAC(2, 0, 0); stageAC(3, 0, 0);
  asm volatile("s_waitcnt vmcnt(0)" ::: "memory");
  __builtin_amdgcn_sched_barrier(0);
  __builtin_amdgcn_s_barrier();
  __builtin_amdgcn_sched_barrier(0);

  for (int t = 0; t < nt; ++t) {
    const int bsel = t & 1;
    const unsigned short* Abuf = lds + bsel * 32768;
    const unsigned short* Bbuf = Abuf + 16384;
    const bool pref = (t + 1 < nt);
    const int nk = (t + 1) * 64;
    const int nb = bsel ^ 1;

    bf16x8 bfr[4][2];
#pragma unroll
    for (int p = 0; p < 4; ++p) {
      // ds_reads: A quadrant p (4 x b128); B all frags at p==0 (8 x b128)
      bf16x8 af[2][2];
#pragma unroll
      for (int i = 0; i < 2; ++i)
#pragma unroll
        for (int ks = 0; ks < 2; ++ks)
          af[i][ks] = *(const bf16x8*)(Abuf + ((wm * 8 + 2 * p + i) * 2 + ks) * 512 + lane * 8);
      if (p == 0) {
#pragma unroll
        for (int nf = 0; nf < 4; ++nf)
#pragma unroll
          for (int ks = 0; ks < 2; ++ks)
            bfr[nf][ks] = *(const bf16x8*)(Bbuf + ((wn * 4 + nf) * 2 + ks) * 512 + lane * 8);
      }
      // staged issue of tile t+1 (order G1..G8 across phases)
      if (pref) {
        if (p == 0) stageBH(0, nk, nb);
        if (p == 1) stageBH(1, nk, nb);
        if (p == 2) { stageAC(0, nk, nb); stageAC(1, nk, nb); }
        if (p == 3) { stageAC(2, nk, nb); stageAC(3, nk, nb); }
      }
      __builtin_amdgcn_s_setprio(1);
#pragma unroll
      for (int i = 0; i < 2; ++i)
#pragma unroll
        for (int nf = 0; nf < 4; ++nf)
#pragma unroll
          for (int ks = 0; ks < 2; ++ks)
            acc[2 * p + i][nf] = __builtin_amdgcn_mfma_f32_16x16x32_bf16(
                af[i][ks], bfr[nf][ks], acc[2 * p + i][nf], 0, 0, 0);
      __builtin_amdgcn_s_setprio(0);
      // counted wavefront forcing (ledger in header)
      if (p == 1) {
        if (pref) asm volatile("s_waitcnt vmcnt(4)" ::: "memory");
        else      asm volatile("s_waitcnt vmcnt(0)" ::: "memory");
      }
      if (p == 3 && pref) asm volatile("s_waitcnt vmcnt(2)" ::: "memory");
      __builtin_amdgcn_sched_barrier(0);
      __builtin_amdgcn_s_barrier();
      __builtin_amdgcn_sched_barrier(0);
    }
  }

  // C/D layout (m89/m91): col = lane&15, row = (lane>>4)*4 + reg
  OutT* Cb = C + bb * sCb + hh * sCh;
#pragma unroll
  for (int mf = 0; mf < 8; ++mf) {
#pragma unroll
    for (int nf = 0; nf < 4; ++nf) {
      const long long col = n0 + wn * 64 + nf * 16 + l15;
#pragma unroll
      for (int r = 0; r < 4; ++r) {
        const long long row = m0 + wm * 128 + mf * 16 + lhi * 4 + r;
        store_val(Cb + (size_t)row * ldc + col, acc[mf][nf][r] * alpha);
      }
    }
  }
}

// ---------------- split-K reduce: out = sum(partials) + bias ----------------
__global__ __launch_bounds__(256) void reduce_kernel(
    const float* __restrict__ P, const float* __restrict__ bias,
    float* __restrict__ out)
{
  const int i = blockIdx.x * 256 + threadIdx.x;      // 0..524287 float4s
  const int col4 = i & 127;
  const float4* p4 = (const float4*)P + i;
  float4 s = p4[0];
#pragma unroll
  for (int z = 1; z < 8; ++z) {
    float4 v = p4[(size_t)z * 524288];
    s.x += v.x; s.y += v.y; s.z += v.z; s.w += v.w;
  }
  float4 b = ((const float4*)bias)[col4];
  s.x += b.x; s.y += b.y; s.z += b.z; s.w += b.w;
  ((float4*)out)[i] = s;
}

// ---------------- fused fp32 -> bf16 cast of all 5 tensors ----------------
__global__ __launch_bounds__(256) void cast5_kernel(
    const float* __restrict__ s0, const float* __restrict__ s1,
    const float* __restrict__ s2, const float* __restrict__ s3,
    const float* __restrict__ s4, unsigned short* __restrict__ dst)
{
  const int seg = blockIdx.x >> 11;
  const int off = (blockIdx.x & 2047) * 256 + threadIdx.x;
  const float* s = s0;
  if (seg == 1) s = s1; else if (seg == 2) s = s2;
  else if (seg == 3) s = s3; else if (seg == 4) s = s4;
  float4 v = ((const float4*)s)[off];
  ushort4 o;
  o.x = f2bf(v.x); o.y = f2bf(v.y); o.z = f2bf(v.z); o.w = f2bf(v.w);
  ((ushort4*)dst)[(size_t)seg * 524288 + off] = o;
}

// ---------------- in-place row softmax over S (bf16), logit = S - mask ----------------
__global__ __launch_bounds__(256) void softmax_kernel(
    unsigned short* __restrict__ S, const float* __restrict__ mask)
{
  const int wave = threadIdx.x >> 6;
  const int lane = threadIdx.x & 63;
  const long long row = (long long)blockIdx.x * 4 + wave;   // 0..32767
  const int q = (int)(row & 1023);
  const int b = (int)(row >> 13);
  unsigned short* Srow = S + row * 1024;
  const float* mrow = mask + ((size_t)b * 1024 + q) * 1024;

  u16x8 sv0 = ((const u16x8*)Srow)[lane * 2];
  u16x8 sv1 = ((const u16x8*)Srow)[lane * 2 + 1];
  float mk[16];
  const float4* m4 = (const float4*)mrow + lane * 4;
#pragma unroll
  for (int t = 0; t < 4; ++t) {
    float4 v = m4[t];
    mk[t * 4 + 0] = v.x; mk[t * 4 + 1] = v.y; mk[t * 4 + 2] = v.z; mk[t * 4 + 3] = v.w;
  }

  float lg[16];
#pragma unroll
  for (int j = 0; j < 8; ++j) lg[j] = bf2f(sv0[j]) - mk[j];
#pragma unroll
  for (int j = 0; j < 8; ++j) lg[8 + j] = bf2f(sv1[j]) - mk[8 + j];

  float mx = lg[0];
#pragma unroll
  for (int j = 1; j < 16; ++j) mx = fmaxf(mx, lg[j]);
#pragma unroll
  for (int off = 32; off > 0; off >>= 1) mx = fmaxf(mx, __shfl_xor(mx, off));

  float ex[16], sm = 0.f;
#pragma unroll
  for (int j = 0; j < 16; ++j) { ex[j] = __expf(lg[j] - mx); sm += ex[j]; }
#pragma unroll
  for (int off = 32; off > 0; off >>= 1) sm += __shfl_xor(sm, off);
  const float rinv = 1.0f / sm;

  u16x8 o0, o1;
#pragma unroll
  for (int j = 0; j < 8; ++j) o0[j] = f2bf(ex[j] * rinv);
#pragma unroll
  for (int j = 0; j < 8; ++j) o1[j] = f2bf(ex[8 + j] * rinv);
  ((u16x8*)Srow)[lane * 2] = o0;
  ((u16x8*)Srow)[lane * 2 + 1] = o1;
}

extern "C" void kernel_launch(void* const* d_in, const int* in_sizes, int n_in,
                              void* d_out, int out_size, void* d_ws, size_t ws_size,
                              hipStream_t stream) {
  const float* x    = (const float*)d_in[0];
  const float* mask = (const float*)d_in[1];
  const float* Wk   = (const float*)d_in[2];
  const float* Wq   = (const float*)d_in[3];
  const float* Wv   = (const float*)d_in[4];
  const float* Wu   = (const float*)d_in[5];
  const float* bu   = (const float*)d_in[6];

  const size_t MB = 1024 * 1024;
  if (ws_size < 212 * MB) return;
  char* ws = (char*)d_ws;
  unsigned short* xb  = (unsigned short*)(ws + 0 * MB);    // 4MB  [4096,512]
  unsigned short* Wqb = (unsigned short*)(ws + 4 * MB);
  unsigned short* Wkb = (unsigned short*)(ws + 8 * MB);
  unsigned short* Wvb = (unsigned short*)(ws + 12 * MB);
  unsigned short* Wub = (unsigned short*)(ws + 16 * MB);
  unsigned short* Qb  = (unsigned short*)(ws + 20 * MB);   // 32MB [b,t,h,e]
  unsigned short* Kb  = (unsigned short*)(ws + 52 * MB);   // 32MB
  unsigned short* Vt  = (unsigned short*)(ws + 84 * MB);   // 32MB [h*e, b*t]
  unsigned short* Sb  = (unsigned short*)(ws + 116 * MB);  // 64MB [b,h,q,k]
  unsigned short* Ob  = (unsigned short*)(ws + 180 * MB);  // 32MB [b,t,h*e]
  float* Pk = (float*)(ws + 20 * MB);  // split-K partials overlay Qb/Kb (dead post-attn)

  cast5_kernel<<<5 * 2048, 256, 0, stream>>>(x, Wq, Wk, Wv, Wu, xb);

  // Q and K projections fused: z=0 -> Wqb/Qb, z=1 -> Wkb/Kb (strides 2M / 16M elems)
  gemm_bt2<unsigned short><<<dim3(16, 16, 2), 512, 0, stream>>>(
      xb, Wqb, Qb, 512, 512, 512, 4096, 0,
      0, 0, 2097152LL, 0, 16777216LL, 0, 1.0f);
  // Vt = Wv.x^T
  gemm_bt2<unsigned short><<<dim3(16, 16, 1), 512, 0, stream>>>(
      Wvb, xb, Vt, 512, 512, 512, 4096, 0, 0, 0, 0, 0, 0, 0, 1.0f);

  // S = (1/sqrt(512)) * Q.K^T per (b,h)   (M=N=1024, K=512, 32 batches)
  gemm_bt2<unsigned short><<<dim3(4, 4, 32), 512, 0, stream>>>(
      Qb, Kb, Sb, 512, 4096, 4096, 1024, 3,
      4194304LL, 512LL, 4194304LL, 512LL, 8388608LL, 1048576LL,
      0.044194173824159216f);

  // P = softmax(S - mask) in place
  softmax_kernel<<<8192, 256, 0, stream>>>(Sb, mask);

  // O = P.V   (M=1024, N=512, K=1024, 32 batches)
  gemm_bt2<unsigned short><<<dim3(2, 4, 32), 512, 0, stream>>>(
      Sb, Vt, Ob, 1024, 1024, 4096, 4096, 3,
      8388608LL, 1048576LL, 1024LL, 2097152LL, 4194304LL, 512LL, 1.0f);

  // out partials: split-K=8 over K=4096 (M=4096, N=512, slice=512)
  gemm_bt2<float><<<dim3(2, 16, 8), 512, 0, stream>>>(
      Ob, Wub, Pk, 512, 4096, 4096, 512, 0,
      512LL, 0, 512LL, 0, 2097152LL, 0, 1.0f);

  // out = sum_z Pk[z] + bu
  reduce_kernel<<<2048, 256, 0, stream>>>(Pk, bu, (float*)d_out);
}